// Round 1
// baseline (1224.750 us; speedup 1.0000x reference)
//
#include <hip/hip_runtime.h>

#define NR 4096
#define NT 96
#define NNZ_CAP 16384
#define LB 128
#define DTSTEP 3600.0f

// ---------- setup: dense int mask -> CSR ----------

__global__ void mc_count(const int* __restrict__ mask, int* __restrict__ counts) {
  int row = blockIdx.x;
  int lane = threadIdx.x;
  const int* r = mask + (size_t)row * NR;
  int c = 0;
  for (int j = lane; j < NR; j += 64) c += (r[j] != 0);
#pragma unroll
  for (int off = 32; off > 0; off >>= 1) c += __shfl_down(c, off);
  if (lane == 0) counts[row] = c;
}

__global__ __launch_bounds__(1024) void mc_scan(const int* __restrict__ counts,
                                                int* __restrict__ rowptr) {
  __shared__ int s[1024];
  int tid = threadIdx.x;
  int c0 = counts[4 * tid + 0];
  int c1 = counts[4 * tid + 1];
  int c2 = counts[4 * tid + 2];
  int c3 = counts[4 * tid + 3];
  int tot = c0 + c1 + c2 + c3;
  s[tid] = tot;
  __syncthreads();
  for (int off = 1; off < 1024; off <<= 1) {
    int add = (tid >= off) ? s[tid - off] : 0;
    __syncthreads();
    s[tid] += add;
    __syncthreads();
  }
  int base = s[tid] - tot;  // exclusive prefix
  rowptr[4 * tid + 0] = base;
  rowptr[4 * tid + 1] = base + c0;
  rowptr[4 * tid + 2] = base + c0 + c1;
  rowptr[4 * tid + 3] = base + c0 + c1 + c2;
  if (tid == 1023) rowptr[NR] = s[1023];
}

__global__ void mc_fill(const int* __restrict__ mask, const int* __restrict__ rowptr,
                        unsigned short* __restrict__ cols) {
  int row = blockIdx.x;
  int lane = threadIdx.x;
  const int* r = mask + (size_t)row * NR;
  int base = rowptr[row];
  for (int j0 = 0; j0 < NR; j0 += 64) {
    int j = j0 + lane;
    int pred = (r[j] != 0);
    unsigned long long m = __ballot(pred);
    if (pred) {
      int pos = __popcll(m & ((1ull << lane) - 1ull));
      int p = base + pos;
      if (p < NNZ_CAP) cols[p] = (unsigned short)j;
    }
    base += __popcll(m);
  }
}

// ---------- routing: single workgroup, everything in LDS ----------

__global__ __launch_bounds__(1024) void mc_route(
    const float* __restrict__ lat, const float* __restrict__ initQ,
    const float* __restrict__ Lg, const float* __restrict__ Sg,
    const float* __restrict__ mng, const float* __restrict__ wcg,
    const float* __restrict__ weg, const float* __restrict__ dcg,
    const float* __restrict__ deg, const int* __restrict__ rowptr_g,
    const unsigned short* __restrict__ cols_g, float* __restrict__ out) {
  __shared__ float Qb0[NR], Qb1[NR], IP[NR], c0s[NR], rhs[NR];  // 80 KB
  __shared__ unsigned short cols_s[NNZ_CAP];                    // 32 KB
  __shared__ unsigned short rp_s[NR + 2];                       // 8 KB
  __shared__ unsigned short order_s[NR];                        // 8 KB
  __shared__ unsigned short level_s[NR];                        // 8 KB
  __shared__ int lvlStart[LB + 1];
  __shared__ int lvlCur[LB];
  __shared__ int flag, nLevels;

  const int tid = threadIdx.x;
  int nnz = rowptr_g[NR];
  if (nnz > NNZ_CAP) nnz = NNZ_CAP;

  for (int i = tid; i <= NR; i += 1024) {
    int v = rowptr_g[i];
    rp_s[i] = (unsigned short)(v > NNZ_CAP ? NNZ_CAP : v);
  }
  for (int e = tid; e < nnz; e += 1024) cols_s[e] = cols_g[e];

#pragma unroll
  for (int k = 0; k < 4; ++k) {
    int i = tid + k * 1024;
    float q = initQ[i];
    Qb0[i] = q;
    Qb1[i] = q;
    IP[i] = 0.f;
    level_s[i] = 0;
  }
  __syncthreads();

  // iterative longest-path level relaxation (monotone; benign LDS races)
  for (int pass = 0; pass < LB; ++pass) {
    if (tid == 0) flag = 0;
    __syncthreads();
    int ch = 0;
#pragma unroll
    for (int k = 0; k < 4; ++k) {
      int i = tid + k * 1024;
      int b = rp_s[i], en = rp_s[i + 1];
      int lv = 0;
      for (int e = b; e < en; ++e) {
        int l2 = (int)level_s[cols_s[e]] + 1;
        lv = lv > l2 ? lv : l2;
      }
      if (lv > LB - 1) lv = LB - 1;
      if (lv > (int)level_s[i]) {
        level_s[i] = (unsigned short)lv;
        ch = 1;
      }
    }
    if (ch) flag = 1;
    __syncthreads();
    int done = (flag == 0);
    __syncthreads();
    if (done) break;
  }

  // counting sort by level -> order_s, lvlStart
  for (int i = tid; i < LB + 1; i += 1024) lvlStart[i] = 0;
  __syncthreads();
#pragma unroll
  for (int k = 0; k < 4; ++k) {
    int i = tid + k * 1024;
    atomicAdd(&lvlStart[(int)level_s[i] + 1], 1);
  }
  __syncthreads();
  if (tid == 0) {
    int nl = 0;
    for (int l = 1; l <= LB; ++l) {
      if (lvlStart[l] > 0) nl = l;  // level l-1 nonempty
      lvlStart[l] += lvlStart[l - 1];
    }
    nLevels = nl;
  }
  __syncthreads();
  for (int i = tid; i < LB; i += 1024) lvlCur[i] = lvlStart[i];
  __syncthreads();
#pragma unroll
  for (int k = 0; k < 4; ++k) {
    int i = tid + k * 1024;
    int p = atomicAdd(&lvlCur[(int)level_s[i]], 1);
    order_s[p] = (unsigned short)i;
  }
  __syncthreads();

  // hoist time-invariant per-reach constants into registers
  float wc_r[4], we_r[4], dc_r[4], de_r[4], vk_r[4], SL_r[4], L_r[4];
#pragma unroll
  for (int k = 0; k < 4; ++k) {
    int i = tid + k * 1024;
    float Lv = Lg[i], Sv = Sg[i], mnv = mng[i];
    float sS = fmaxf(Sv, 1e-6f);
    vk_r[k] = sqrtf(sS) / fmaxf(mnv, 1e-3f);
    SL_r[k] = sS * Lv;
    L_r[k] = Lv;
    wc_r[k] = wcg[i];
    we_r[k] = weg[i];
    dc_r[k] = dcg[i];
    de_r[k] = deg[i];
  }

  float* Qold = Qb0;  // Q_{t-1}
  float* Qnew = Qb1;  // holds Q_{t-2}; becomes Q_t during solve
  const int nlev = nLevels;

  for (int t = 0; t < NT; ++t) {
    // phase 1: coefficients + rhs (Q_out = c0*upstream + rhs, all terms >= 0)
#pragma unroll
    for (int k = 0; k < 4; ++k) {
      int i = tid + k * 1024;
      float latv = lat[t * NR + i];
      float Qref = fmaxf(Qold[i], 0.1f);
      float lq = __logf(Qref);
      float W = wc_r[k] * __expf(we_r[k] * lq);
      float Dd = dc_r[k] * __expf(de_r[k] * lq);
      float R = (W * Dd) / (W + 2.f * Dd);
      float V = vk_r[k] * __expf(0.66666667f * __logf(fmaxf(R, 1e-6f)));
      float c = fmaxf((5.f / 3.f) * V, 0.01f);
      float K = fmaxf(L_r[k] / c, 0.1f * DTSTEP);
      float X = 0.5f * (1.f - Qref / (W * c * SL_r[k] + 1e-6f));
      X = fminf(fmaxf(X, 0.f), 0.5f);
      float twoKX = 2.f * K * X;
      float twoK1X = 2.f * K * (1.f - X);
      // den cancels under normalization: coeff_i = max(num_i,0)/sum(max(num_j,0))
      float C0 = fmaxf(DTSTEP - twoKX, 0.f);
      float C1 = DTSTEP + twoKX;  // always >= 0
      float C2 = fmaxf(twoK1X - DTSTEP, 0.f);
      float inv = 1.f / (C0 + C1 + C2);
      float c0n = C0 * inv;
      rhs[i] = c0n * latv + (C1 * inv) * IP[i] + (C2 * inv) * Qnew[i];
      c0s[i] = c0n;
      IP[i] = latv;  // will accumulate upstream sum during solve -> I_t
    }
    __syncthreads();

    // phase 2: level-scheduled sparse lower-triangular solve
    for (int l = 0; l < nlev; ++l) {
      int e0 = lvlStart[l], e1 = lvlStart[l + 1];
      for (int idx = e0 + tid; idx < e1; idx += 1024) {
        int i = order_s[idx];
        float s = 0.f;
        int b = rp_s[i], en = rp_s[i + 1];
        for (int e = b; e < en; ++e) s += Qnew[cols_s[e]];
        IP[i] = s + IP[i];
        Qnew[i] = fmaxf(c0s[i] * s + rhs[i], 0.f);
      }
      __syncthreads();
    }

    if (tid == 0) out[t] = Qnew[NR - 1];
    float* tmp = Qold;
    Qold = Qnew;
    Qnew = tmp;
  }
}

extern "C" void kernel_launch(void* const* d_in, const int* in_sizes, int n_in,
                              void* d_out, int out_size, void* d_ws, size_t ws_size,
                              hipStream_t stream) {
  const float* lat = (const float*)d_in[0];
  const float* iQ = (const float*)d_in[1];
  const float* Lg = (const float*)d_in[2];
  const float* Sg = (const float*)d_in[3];
  const float* mng = (const float*)d_in[4];
  const float* wcg = (const float*)d_in[5];
  const float* weg = (const float*)d_in[6];
  const float* dcg = (const float*)d_in[7];
  const float* deg = (const float*)d_in[8];
  const int* mask = (const int*)d_in[9];
  float* out = (float*)d_out;

  int* counts = (int*)d_ws;                                    // 4096 ints
  int* rowptr = counts + NR;                                   // 4097 ints
  unsigned short* cols = (unsigned short*)(rowptr + NR + 4);   // NNZ_CAP u16

  mc_count<<<NR, 64, 0, stream>>>(mask, counts);
  mc_scan<<<1, 1024, 0, stream>>>(counts, rowptr);
  mc_fill<<<NR, 64, 0, stream>>>(mask, rowptr, cols);
  mc_route<<<1, 1024, 0, stream>>>(lat, iQ, Lg, Sg, mng, wcg, weg, dcg, deg,
                                   rowptr, cols, out);
}